// Round 1
// baseline (361.483 us; speedup 1.0000x reference)
//
#include <hip/hip_runtime.h>
#include <math.h>

#define D_DIM 160
#define H_DIM 192
#define W_DIM 192
#define HWN   (H_DIM * W_DIM)                 // 36864
#define NTOT  ((size_t)D_DIM * H_DIM * W_DIM) // 5898240

#define C1 0.0001f   // 0.01^2
#define C2 0.0009f   // 0.03^2

#define TW 64
#define TH 16
#define HALO 5
#define IW (TW + 2 * HALO)   // 74
#define IH (TH + 2 * HALO)   // 26

struct GaussW { float g[11]; };

// Pass 1: products + W-blur + H-blur (zero padding), per d-slice, LDS tiled.
__global__ __launch_bounds__(256) void ssim_pass1(
    const float* __restrict__ img1, const float* __restrict__ img2,
    float* __restrict__ fields, GaussW gwts)
{
    __shared__ float s1[IH][IW];
    __shared__ float s2[IH][IW];
    __shared__ float tmp[5][IH][TW];

    const int tid = threadIdx.x;
    const int w0 = blockIdx.x * TW;
    const int h0 = blockIdx.y * TH;
    const int d  = blockIdx.z;

    const float* base1 = img1 + (size_t)d * HWN;
    const float* base2 = img2 + (size_t)d * HWN;

    // stage input tile with halo (zero pad outside image)
    for (int i = tid; i < IH * IW; i += 256) {
        int r = i / IW, c = i - r * IW;
        int gh = h0 + r - HALO;
        int gw = w0 + c - HALO;
        float a = 0.f, b = 0.f;
        if (gh >= 0 && gh < H_DIM && gw >= 0 && gw < W_DIM) {
            a = base1[gh * W_DIM + gw];
            b = base2[gh * W_DIM + gw];
        }
        s1[r][c] = a;
        s2[r][c] = b;
    }
    __syncthreads();

    // W-blur of the 5 product fields (products formed on the fly)
    for (int i = tid; i < IH * TW; i += 256) {
        int r = i >> 6, c = i & 63;
        float a0 = 0.f, a1 = 0.f, a2 = 0.f, a3 = 0.f, a4 = 0.f;
#pragma unroll
        for (int k = 0; k < 11; ++k) {
            float wgt = gwts.g[k];
            float x = s1[r][c + k];
            float y = s2[r][c + k];
            a0 += wgt * x;
            a1 += wgt * y;
            a2 += wgt * x * x;
            a3 += wgt * y * y;
            a4 += wgt * x * y;
        }
        tmp[0][r][c] = a0;
        tmp[1][r][c] = a1;
        tmp[2][r][c] = a2;
        tmp[3][r][c] = a3;
        tmp[4][r][c] = a4;
    }
    __syncthreads();

    // H-blur + store the 5 fields
    for (int i = tid; i < TH * TW; i += 256) {
        int r = i >> 6, c = i & 63;
        size_t o = (size_t)d * HWN + (size_t)(h0 + r) * W_DIM + (w0 + c);
#pragma unroll
        for (int f = 0; f < 5; ++f) {
            float acc = 0.f;
#pragma unroll
            for (int k = 0; k < 11; ++k) acc += gwts.g[k] * tmp[f][r + k][c];
            fields[(size_t)f * NTOT + o] = acc;
        }
    }
}

// Pass 2: D-blur gather + SSIM + block reduce -> double atomic accumulate
__global__ __launch_bounds__(256) void ssim_pass2(
    const float* __restrict__ fields, double* __restrict__ accum, GaussW gwts)
{
    size_t idx = (size_t)blockIdx.x * 256 + threadIdx.x;
    float ssim = 0.f;
    if (idx < NTOT) {
        int d  = (int)(idx / HWN);
        int hw = (int)(idx - (size_t)d * HWN);
        float m0 = 0.f, m1 = 0.f, m2 = 0.f, m3 = 0.f, m4 = 0.f;
#pragma unroll
        for (int k = 0; k < 11; ++k) {
            int dd = d + k - 5;
            if (dd >= 0 && dd < D_DIM) {
                float wgt = gwts.g[k];
                size_t off = (size_t)dd * HWN + hw;
                m0 += wgt * fields[off];
                m1 += wgt * fields[NTOT + off];
                m2 += wgt * fields[2 * NTOT + off];
                m3 += wgt * fields[3 * NTOT + off];
                m4 += wgt * fields[4 * NTOT + off];
            }
        }
        float mu1sq = m0 * m0;
        float mu2sq = m1 * m1;
        float mu12  = m0 * m1;
        float s1sq  = m2 - mu1sq;
        float s2sq  = m3 - mu2sq;
        float s12   = m4 - mu12;
        ssim = ((2.f * mu12 + C1) * (2.f * s12 + C2)) /
               ((mu1sq + mu2sq + C1) * (s1sq + s2sq + C2));
    }

    // wave (64-lane) shuffle reduce, then cross-wave via LDS
    for (int off = 32; off > 0; off >>= 1)
        ssim += __shfl_down(ssim, off, 64);
    __shared__ float wsum[4];
    int lane = threadIdx.x & 63;
    int wv   = threadIdx.x >> 6;
    if (lane == 0) wsum[wv] = ssim;
    __syncthreads();
    if (threadIdx.x == 0) {
        float bs = wsum[0] + wsum[1] + wsum[2] + wsum[3];
        atomicAdd(accum, (double)bs);
    }
}

__global__ void ssim_finalize(const double* __restrict__ accum,
                              float* __restrict__ out)
{
    out[0] = (float)(accum[0] / (double)NTOT);
}

extern "C" void kernel_launch(void* const* d_in, const int* in_sizes, int n_in,
                              void* d_out, int out_size, void* d_ws, size_t ws_size,
                              hipStream_t stream)
{
    const float* img1 = (const float*)d_in[0];
    const float* img2 = (const float*)d_in[1];
    float* out = (float*)d_out;

    // host-side gaussian (double precision, matches reference to f32 rounding)
    GaussW gwts;
    {
        double raw[11], sum = 0.0;
        for (int i = 0; i < 11; ++i) {
            double x = (double)i - 5.0;
            raw[i] = exp(-(x * x) / (2.0 * 1.5 * 1.5));
            sum += raw[i];
        }
        for (int i = 0; i < 11; ++i) gwts.g[i] = (float)(raw[i] / sum);
    }

    float* fields = (float*)d_ws;                          // 5 * NTOT floats
    double* accum = (double*)((char*)d_ws + 5 * NTOT * 4); // 8B, 8-aligned

    hipMemsetAsync(accum, 0, sizeof(double), stream);

    dim3 g1(W_DIM / TW, H_DIM / TH, D_DIM); // (3, 12, 160)
    ssim_pass1<<<g1, 256, 0, stream>>>(img1, img2, fields, gwts);

    int nblk2 = (int)((NTOT + 255) / 256); // 23040
    ssim_pass2<<<nblk2, 256, 0, stream>>>(fields, accum, gwts);

    ssim_finalize<<<1, 1, 0, stream>>>(accum, out);
}

// Round 2
// 109.868 us; speedup vs baseline: 3.2901x; 3.2901x over previous
//
#include <hip/hip_runtime.h>
#include <math.h>

#define D_DIM 160
#define H_DIM 192
#define W_DIM 192
#define HWN   (H_DIM * W_DIM)                 // 36864
#define NTOT  ((size_t)D_DIM * H_DIM * W_DIM) // 5898240

#define C1 0.0001f   // 0.01^2
#define C2 0.0009f   // 0.03^2

#define TW 64
#define TH 16
#define HALO 5
#define IW (TW + 2 * HALO)   // 74
#define IH (TH + 2 * HALO)   // 26

#define DC 22                // d-outputs per pass2 block (2*11 -> static slots)
#define DCHUNKS 8            // 8*22 = 176 >= 160

struct GaussW { float g[11]; };

// Pass 1: products + W-blur + H-blur (zero padding), per d-slice, LDS tiled.
__global__ __launch_bounds__(256) void ssim_pass1(
    const float* __restrict__ img1, const float* __restrict__ img2,
    float* __restrict__ fields, GaussW gwts)
{
    __shared__ float s1[IH][IW];
    __shared__ float s2[IH][IW];
    __shared__ float tmp[5][IH][TW];

    const int tid = threadIdx.x;
    const int w0 = blockIdx.x * TW;
    const int h0 = blockIdx.y * TH;
    const int d  = blockIdx.z;

    const float* base1 = img1 + (size_t)d * HWN;
    const float* base2 = img2 + (size_t)d * HWN;

    // stage input tile with halo (zero pad outside image)
    for (int i = tid; i < IH * IW; i += 256) {
        int r = i / IW, c = i - r * IW;
        int gh = h0 + r - HALO;
        int gw = w0 + c - HALO;
        float a = 0.f, b = 0.f;
        if (gh >= 0 && gh < H_DIM && gw >= 0 && gw < W_DIM) {
            a = base1[gh * W_DIM + gw];
            b = base2[gh * W_DIM + gw];
        }
        s1[r][c] = a;
        s2[r][c] = b;
    }
    __syncthreads();

    // W-blur of the 5 product fields (products formed on the fly)
    for (int i = tid; i < IH * TW; i += 256) {
        int r = i >> 6, c = i & 63;
        float a0 = 0.f, a1 = 0.f, a2 = 0.f, a3 = 0.f, a4 = 0.f;
#pragma unroll
        for (int k = 0; k < 11; ++k) {
            float wgt = gwts.g[k];
            float x = s1[r][c + k];
            float y = s2[r][c + k];
            a0 += wgt * x;
            a1 += wgt * y;
            a2 += wgt * x * x;
            a3 += wgt * y * y;
            a4 += wgt * x * y;
        }
        tmp[0][r][c] = a0;
        tmp[1][r][c] = a1;
        tmp[2][r][c] = a2;
        tmp[3][r][c] = a3;
        tmp[4][r][c] = a4;
    }
    __syncthreads();

    // H-blur + store the 5 fields
    for (int i = tid; i < TH * TW; i += 256) {
        int r = i >> 6, c = i & 63;
        size_t o = (size_t)d * HWN + (size_t)(h0 + r) * W_DIM + (w0 + c);
#pragma unroll
        for (int f = 0; f < 5; ++f) {
            float acc = 0.f;
#pragma unroll
            for (int k = 0; k < 11; ++k) acc += gwts.g[k] * tmp[f][r + k][c];
            fields[(size_t)f * NTOT + o] = acc;
        }
    }
}

// Pass 2: rolling-window D-blur + SSIM + block reduce -> double atomic.
// Each thread owns one hw column; marches DC outputs along d, loading each
// plane of each field exactly once. All window indices compile-time (full
// unroll) so the 5x11 window lives in registers.
__global__ __launch_bounds__(256) void ssim_pass2(
    const float* __restrict__ fields, double* __restrict__ accum, GaussW gwts)
{
    const int hw = blockIdx.x * 256 + threadIdx.x;  // 144 blocks cover HWN
    const int d0 = blockIdx.y * DC;

    float win[5][11];

    // prologue: planes d0-5 .. d0+4 -> slots 0..9 (zero outside volume)
#pragma unroll
    for (int i = 0; i < 10; ++i) {
        int p = d0 - 5 + i;
        bool ok = (p >= 0) && (p < D_DIM);
        size_t off = (size_t)(ok ? p : 0) * HWN + hw;
#pragma unroll
        for (int f = 0; f < 5; ++f)
            win[f][i] = ok ? fields[(size_t)f * NTOT + off] : 0.f;
    }

    float ssum = 0.f;
#pragma unroll
    for (int j = 0; j < DC; ++j) {
        const int d = d0 + j;
        // incoming plane d+5 -> slot (j+10)%11
        {
            int p = d + 5;
            bool ok = (p < D_DIM);
            size_t off = (size_t)(ok ? p : 0) * HWN + hw;
#pragma unroll
            for (int f = 0; f < 5; ++f)
                win[f][(j + 10) % 11] = ok ? fields[(size_t)f * NTOT + off] : 0.f;
        }
        if (d < D_DIM) {
            float m[5];
#pragma unroll
            for (int f = 0; f < 5; ++f) {
                float acc = 0.f;
#pragma unroll
                for (int k = 0; k < 11; ++k)
                    acc += gwts.g[k] * win[f][(j + k) % 11];
                m[f] = acc;
            }
            float mu1sq = m[0] * m[0];
            float mu2sq = m[1] * m[1];
            float mu12  = m[0] * m[1];
            float s1sq  = m[2] - mu1sq;
            float s2sq  = m[3] - mu2sq;
            float s12   = m[4] - mu12;
            ssum += ((2.f * mu12 + C1) * (2.f * s12 + C2)) /
                    ((mu1sq + mu2sq + C1) * (s1sq + s2sq + C2));
        }
    }

    // wave (64-lane) shuffle reduce, then cross-wave via LDS
    for (int off = 32; off > 0; off >>= 1)
        ssum += __shfl_down(ssum, off, 64);
    __shared__ float wsum[4];
    int lane = threadIdx.x & 63;
    int wv   = threadIdx.x >> 6;
    if (lane == 0) wsum[wv] = ssum;
    __syncthreads();
    if (threadIdx.x == 0) {
        float bs = wsum[0] + wsum[1] + wsum[2] + wsum[3];
        atomicAdd(accum, (double)bs);
    }
}

__global__ void ssim_finalize(const double* __restrict__ accum,
                              float* __restrict__ out)
{
    out[0] = (float)(accum[0] / (double)NTOT);
}

extern "C" void kernel_launch(void* const* d_in, const int* in_sizes, int n_in,
                              void* d_out, int out_size, void* d_ws, size_t ws_size,
                              hipStream_t stream)
{
    const float* img1 = (const float*)d_in[0];
    const float* img2 = (const float*)d_in[1];
    float* out = (float*)d_out;

    // host-side gaussian (double precision, matches reference to f32 rounding)
    GaussW gwts;
    {
        double raw[11], sum = 0.0;
        for (int i = 0; i < 11; ++i) {
            double x = (double)i - 5.0;
            raw[i] = exp(-(x * x) / (2.0 * 1.5 * 1.5));
            sum += raw[i];
        }
        for (int i = 0; i < 11; ++i) gwts.g[i] = (float)(raw[i] / sum);
    }

    float* fields = (float*)d_ws;                          // 5 * NTOT floats
    double* accum = (double*)((char*)d_ws + 5 * NTOT * 4); // 8B, 8-aligned

    hipMemsetAsync(accum, 0, sizeof(double), stream);

    dim3 g1(W_DIM / TW, H_DIM / TH, D_DIM); // (3, 12, 160)
    ssim_pass1<<<g1, 256, 0, stream>>>(img1, img2, fields, gwts);

    dim3 g2(HWN / 256, DCHUNKS); // (144, 8)
    ssim_pass2<<<g2, 256, 0, stream>>>(fields, accum, gwts);

    ssim_finalize<<<1, 1, 0, stream>>>(accum, out);
}